// Round 2
// baseline (3132.510 us; speedup 1.0000x reference)
//
#include <hip/hip_runtime.h>

#define TT   2048
#define BB   512
#define IN_  27
#define HH   64
#define OUTD 26
#define EPSV 1e-5f

__device__ __forceinline__ float bcastf(float v, int lane) {
    return __int_as_float(__builtin_amdgcn_readlane(__float_as_int(v), lane));
}

__device__ __forceinline__ float sigm(float x) {
    return 1.0f / (1.0f + __expf(-x));
}

__device__ __forceinline__ float tanh_fast(float x) {
    float e = __expf(-2.0f * fabsf(x));
    float r = (1.0f - e) / (1.0f + e);
    return copysignf(r, x);
}

// Phase 1: sequential LSTM. ONE WAVE per batch element; lane l owns h[l],c[l]
// and all four gates {i,f,g,o} for h-index l (4 accumulators). Each of the 91
// broadcast values (h and prefetched x via readlane) feeds 4 FMAs. Cell
// update is lane-local: NO LDS, NO barrier anywhere in the timestep loop.
// Weights register-resident: 4*(27+64)=364 VGPRs + state ~= 400 < 512
// (__launch_bounds__(64,1) allows the full single-wave register file).
// 512 waves over 1024 SIMDs -> every wave gets its own SIMD; occupancy
// limits don't bind, only the serial chain length does.
__global__ __launch_bounds__(64, 1) void lstm_seq(
    const float* __restrict__ x,     // [T,B,IN]
    const float* __restrict__ W_ih,  // [4H,IN]
    const float* __restrict__ W_hh,  // [4H,H]
    const float* __restrict__ b_ih,  // [4H]
    const float* __restrict__ b_hh,  // [4H]
    float* __restrict__ h_all,       // [tc,B,H] (workspace)
    float* __restrict__ state,       // [2,B,H]  (workspace: h then c)
    int t0, int tc, int first)
{
    const int b = blockIdx.x;
    const int l = threadIdx.x;       // 0..63 = h index

    // gate rows: j = q*64 + l  (q: 0=i 1=f 2=g 3=o)
    float wi[4][IN_];
    float wh[4][HH];
    float bias[4];
#pragma unroll
    for (int q = 0; q < 4; ++q) {
        const int j = q * HH + l;
#pragma unroll
        for (int k = 0; k < IN_; ++k) wi[q][k] = W_ih[j * IN_ + k];
#pragma unroll
        for (int k = 0; k < HH; ++k) wh[q][k] = W_hh[j * HH + k];
        bias[q] = b_ih[j] + b_hh[j];
    }

    float hv, cv;
    if (first) {
        hv = 0.0f; cv = 0.0f;
    } else {
        hv = state[b * HH + l];
        cv = state[BB * HH + b * HH + l];
    }

    // Prefetch x row for t0 (lanes 0..26; others compute but never use it).
    float xv = (l < IN_) ? x[((size_t)t0 * BB + b) * IN_ + l] : 0.0f;

#pragma unroll 1
    for (int tl = 0; tl < tc; ++tl) {
        const int t = t0 + tl;

        // Rotate prefetch: consume xv this step, issue load for t+1 now so
        // its HBM/L2 latency hides under the 320-instr dot-product below.
        const float xcur = xv;
        int tn = t + 1; if (tn > TT - 1) tn = TT - 1;   // clamp (last step)
        xv = (l < IN_) ? x[((size_t)tn * BB + b) * IN_ + l] : 0.0f;

        float a0 = bias[0], a1 = bias[1], a2 = bias[2], a3 = bias[3];

        // h-dot: one readlane broadcast feeds 4 FMAs. Same-accumulator dep
        // spacing is 5 instrs (~10 cyc wave64) > 4-cyc FMA latency: no stall.
#pragma unroll
        for (int k = 0; k < HH; ++k) {
            const float hk = bcastf(hv, k);
            a0 = fmaf(hk, wh[0][k], a0);
            a1 = fmaf(hk, wh[1][k], a1);
            a2 = fmaf(hk, wh[2][k], a2);
            a3 = fmaf(hk, wh[3][k], a3);
        }
        // x-dot
#pragma unroll
        for (int k = 0; k < IN_; ++k) {
            const float xk = bcastf(xcur, k);
            a0 = fmaf(xk, wi[0][k], a0);
            a1 = fmaf(xk, wi[1][k], a1);
            a2 = fmaf(xk, wi[2][k], a2);
            a3 = fmaf(xk, wi[3][k], a3);
        }

        const float gi = sigm(a0);
        const float gf = sigm(a1);
        const float gg = tanh_fast(a2);
        const float go = sigm(a3);

        cv = fmaf(gf, cv, gi * gg);
        hv = go * tanh_fast(cv);

        // coalesced 256B store per wave, fire-and-forget
        h_all[((size_t)tl * BB + b) * HH + l] = hv;
    }

    state[b * HH + l] = hv;
    state[BB * HH + b * HH + l] = cv;
}

// Phase 2: per-timestep BatchNorm (batch stats) + locked dropout + maxpool
// over batch + FC. One block per timestep, fully parallel over tc.
// Unchanged from the verified round-0 kernel (~150us total).
__global__ __launch_bounds__(256, 2) void bn_pool_fc(
    const float* __restrict__ h_all,  // [tc,B,H]
    const float* __restrict__ gamma,  // [H]
    const float* __restrict__ beta,   // [H]
    const float* __restrict__ dmask,  // [B,H]
    const float* __restrict__ pg,     // [T,OUT]
    const float* __restrict__ W_fc,   // [OUT, H+OUT]
    const float* __restrict__ b_fc,   // [OUT]
    float* __restrict__ y,            // [T,OUT]
    int t0, int tc)
{
    const int tl = blockIdx.x;
    const int t = t0 + tl;
    const int tid = threadIdx.x;
    const int g = tid >> 6;      // 4 batch groups
    const int hcol = tid & 63;
    const float* hp = h_all + (size_t)tl * BB * HH;

    __shared__ float s_a[4][HH];
    __shared__ float s_b[4][HH];
    __shared__ float s_scale[HH];
    __shared__ float s_shift[HH];
    __shared__ float s_pool[HH];

    // pass 1: sum and sumsq over batch (coalesced: lane = hcol)
    float sum = 0.0f, sq = 0.0f;
    for (int bb = g; bb < BB; bb += 4) {
        const float v = hp[bb * HH + hcol];
        sum += v;
        sq = fmaf(v, v, sq);
    }
    s_a[g][hcol] = sum;
    s_b[g][hcol] = sq;
    __syncthreads();

    if (tid < HH) {
        const float s  = (s_a[0][tid] + s_a[1][tid]) + (s_a[2][tid] + s_a[3][tid]);
        const float q2 = (s_b[0][tid] + s_b[1][tid]) + (s_b[2][tid] + s_b[3][tid]);
        const float mean = s * (1.0f / BB);
        const float var  = q2 * (1.0f / BB) - mean * mean;  // biased var
        const float rs = rsqrtf(var + EPSV);
        const float sc = rs * gamma[tid];
        s_scale[tid] = sc;
        s_shift[tid] = beta[tid] - mean * sc;
    }
    __syncthreads();

    // pass 2: normalize + locked dropout + max over batch
    const float sc = s_scale[hcol];
    const float sh = s_shift[hcol];
    float m = -3.0e38f;
    for (int bb = g; bb < BB; bb += 4) {
        const float v = hp[bb * HH + hcol];
        const float hd = fmaf(v, sc, sh) * dmask[bb * HH + hcol];
        m = fmaxf(m, hd);
    }
    s_a[g][hcol] = m;
    __syncthreads();
    if (tid < HH) {
        s_pool[tid] = fmaxf(fmaxf(s_a[0][tid], s_a[1][tid]),
                            fmaxf(s_a[2][tid], s_a[3][tid]));
    }
    __syncthreads();

    // FC: y[t, o] = b_fc[o] + W_fc[o, 0:64].pool + W_fc[o, 64:90].pg[t]
    if (tid < OUTD) {
        float acc = b_fc[tid];
        const float* w = W_fc + tid * (HH + OUTD);
#pragma unroll
        for (int k = 0; k < HH; ++k) acc = fmaf(w[k], s_pool[k], acc);
#pragma unroll
        for (int k = 0; k < OUTD; ++k) acc = fmaf(w[HH + k], pg[t * OUTD + k], acc);
        y[t * OUTD + tid] = acc;
    }
}

extern "C" void kernel_launch(void* const* d_in, const int* in_sizes, int n_in,
                              void* d_out, int out_size, void* d_ws, size_t ws_size,
                              hipStream_t stream)
{
    const float* x     = (const float*)d_in[0];   // [T,B,IN]
    const float* pg    = (const float*)d_in[1];   // [T,OUT]
    const float* W_ih  = (const float*)d_in[2];   // [4H,IN]
    const float* W_hh  = (const float*)d_in[3];   // [4H,H]
    const float* b_ih  = (const float*)d_in[4];
    const float* b_hh  = (const float*)d_in[5];
    const float* gamma = (const float*)d_in[6];
    const float* beta  = (const float*)d_in[7];
    const float* W_fc  = (const float*)d_in[8];   // [OUT,H+OUT]
    const float* b_fc  = (const float*)d_in[9];
    const float* dmask = (const float*)d_in[10];  // [B,H]
    float* y = (float*)d_out;

    // Workspace: h_all[chunkT, B, H] fp32 + carried state h,c [2,B,H].
    const size_t state_bytes = 2ull * BB * HH * sizeof(float);
    const size_t per_t = (size_t)BB * HH * sizeof(float);
    size_t avail = (ws_size > state_bytes) ? (ws_size - state_bytes) : 0;
    int chunkT = (int)(avail / per_t);
    if (chunkT > TT) chunkT = TT;
    if (chunkT < 1) chunkT = 1;

    float* h_all = (float*)d_ws;
    float* state = (float*)((char*)d_ws + (size_t)chunkT * per_t);

    int first = 1;
    for (int t0 = 0; t0 < TT; t0 += chunkT) {
        int tc = TT - t0;
        if (tc > chunkT) tc = chunkT;
        lstm_seq<<<BB, 64, 0, stream>>>(x, W_ih, W_hh, b_ih, b_hh,
                                        h_all, state, t0, tc, first);
        bn_pool_fc<<<tc, 256, 0, stream>>>(h_all, gamma, beta, dmask, pg,
                                           W_fc, b_fc, y, t0, tc);
        first = 0;
    }
}